// Round 7
// baseline (569.241 us; speedup 1.0000x reference)
//
#include <hip/hip_runtime.h>

#define DIM   256
#define BATCH 16
#define NPX   (DIM*DIM)

// padded ws layout: rows gy+12 in [0,280), col stride 284 (16B-aligned rows)
// fields use col offset +12 (tile col base bx*64 -> aligned float4)
// coeffs use col offset +13 (epilogue col base bx*64+4+4cg -> aligned float4)
#define PR   280
#define PC   284
#define PBS  (PR*PC)                 // 79520 floats per batch
#define NPAD ((size_t)BATCH*PBS)     // 1,272,320 floats per array

// LDS tile: 88x88 region used, 90 rows (2 pad-read rows), stride 92 (16B-aligned)
#define LR 90
#define LC 92

// Collapse the 14 used fd_kernels into one effective 7x7 kernel.
// eff[t] = sum_{c=1..14} fdk[c,0,t] * cw[c-1]   (kernel 0 unused: u1fd[:,1:])
__global__ void prep_eff(const float* __restrict__ fdk,
                         const float* __restrict__ cw,
                         float* __restrict__ eff) {
    int t = threadIdx.x;
    if (t < 49) {
        float s = 0.f;
        #pragma unroll
        for (int c = 1; c < 15; ++c)
            s += fdk[c * 49 + t] * cw[c - 1];
        eff[t] = s;
    }
}

// Streaming prologue: build padded A1/A0 (= u1,u0 with zero border), zero B1/B0,
// and precompute D1 = 1/(4e+sg), G = (4e-sg)*D1 into padded CD/CG.
__global__ __launch_bounds__(256) void prologue(
    const float* __restrict__ u1, const float* __restrict__ u0,
    const float* __restrict__ epsr, const float* __restrict__ sigma,
    float* __restrict__ A1, float* __restrict__ A0,
    float* __restrict__ B1, float* __restrict__ B0,
    float* __restrict__ CD, float* __restrict__ CG)
{
    const int i4 = blockIdx.x * 256 + threadIdx.x;
    const int percb = PR * (PC / 4);            // 19,880 float4 per batch
    if (i4 >= BATCH * percb) return;
    const int b   = i4 / percb;
    const int rem = i4 - b * percb;
    const int row = rem / (PC / 4);
    const int col = (rem - row * (PC / 4)) * 4;
    const size_t cell = (size_t)b * PBS + (size_t)row * PC + col;
    const size_t gb   = (size_t)b * NPX;
    const int gy = row - 12;

    float f1[4], f0[4], cd[4], cg2[4];
    #pragma unroll
    for (int j = 0; j < 4; ++j) {
        const int gxf = col + j - 12;           // field col
        const int gxc = col + j - 13;           // coeff col
        float v1 = 0.f, v0 = 0.f, d = 0.f, g = 0.f;
        if (gy >= 0 && gy < DIM && gxf >= 0 && gxf < DIM) {
            v1 = u1[gb + gy * DIM + gxf];
            v0 = u0[gb + gy * DIM + gxf];
        }
        if (gy >= 0 && gy < DIM && gxc >= 0 && gxc < DIM) {
            const float e = epsr[gb + gy * DIM + gxc];
            const float s = sigma[gb + gy * DIM + gxc];
            d = 1.f / (4.f * e + s);            // exact div once, reused 32x
            g = (4.f * e - s) * d;
        }
        f1[j] = v1; f0[j] = v0; cd[j] = d; cg2[j] = g;
    }
    *(float4*)&A1[cell] = make_float4(f1[0], f1[1], f1[2], f1[3]);
    *(float4*)&A0[cell] = make_float4(f0[0], f0[1], f0[2], f0[3]);
    *(float4*)&CD[cell] = make_float4(cd[0], cd[1], cd[2], cd[3]);
    *(float4*)&CG[cell] = make_float4(cg2[0], cg2[1], cg2[2], cg2[3]);
    const float4 z = make_float4(0.f, 0.f, 0.f, 0.f);
    *(float4*)&B1[cell] = z;
    *(float4*)&B0[cell] = z;
}

// 4 FDTD steps per launch. 256 blocks (4,4,16) = 1/CU, 1024 threads = 16 waves.
// __launch_bounds__(1024, 1): min 1 block/CU -> VGPR cap 128 (the ",4" in round
// 6 clamped the cap to 64 and spilled ~190 MB/dispatch of scratch traffic).
// Fixed ownership: thread t<441 owns a 4x4 pixel block of the 82^2 region for
// ALL substeps (out-of-region pixels are computed but provably never consumed).
__global__ __launch_bounds__(1024, 1) void fdtd4(
    const float* __restrict__ U1, const float* __restrict__ U0,   // padded
    const float* __restrict__ CD, const float* __restrict__ CG,   // padded
    const float* __restrict__ eff, const float* __restrict__ src,
    float* __restrict__ NU1, int n1bs, int n1rs, int n1off,
    float* __restrict__ NU0,                                      // padded
    int sbase)
{
    __shared__ __align__(16) float F[2][LR][LC];

    const int t  = threadIdx.x;
    const int bx = blockIdx.x, by = blockIdx.y, b = blockIdx.z;
    const int x0g = bx * 64 - 12, y0g = by * 64 - 12;
    const size_t pb = (size_t)b * PBS;

    // ---- stage F0 <- u_s, F1 <- u_{s-1}: 88 rows x 22 float4, no guards ----
    {
        const float* s1 = U1 + pb;
        const float* s0 = U0 + pb;
        #pragma unroll
        for (int rep = 0; rep < 2; ++rep) {
            const int i = t + rep * 1024;
            if (i < 88 * 22) {
                const int row = i / 22, q = (i - row * 22) * 4;
                const size_t g = (size_t)(by * 64 + row) * PC + (bx * 64 + q);
                *(float4*)&F[0][row][q] = *(const float4*)&s1[g];
                *(float4*)&F[1][row][q] = *(const float4*)&s0[g];
            }
        }
    }

    // ---- fixed ownership + coefficient registers (no guards: padded arrays) ----
    const int band = t / 21, cg = t - band * 21;        // t<441: 21x21 4x4-blocks
    const int ly0 = 3 + 4 * band, lx0 = 3 + 4 * cg;
    const int nR = (band == 20) ? 2 : 4;
    const int nC = (cg  == 20) ? 2 : 4;
    float cdv[4][4], cgv[4][4];
    if (t < 441) {
        #pragma unroll
        for (int k = 0; k < 4; ++k) {
            const size_t ci = pb + (size_t)(y0g + ly0 + k + 12) * PC
                                 + (x0g + lx0 + 13);
            const float4 d = *(const float4*)&CD[ci];
            const float4 g = *(const float4*)&CG[ci];
            cdv[k][0] = d.x; cdv[k][1] = d.y; cdv[k][2] = d.z; cdv[k][3] = d.w;
            cgv[k][0] = g.x; cgv[k][1] = g.y; cgv[k][2] = g.z; cgv[k][3] = g.w;
        }
    }
    __syncthreads();

    // ---- 4 substeps; code emitted ONCE (runtime sb loop keeps I$ small) ----
    #pragma unroll 1
    for (int sb = 0; sb < 4; ++sb) {
        if (t < 441) {
            const float (*Fs)[LC] = F[sb & 1];          // u_{s+sb}
            float (*Fd)[LC]       = F[(sb & 1) ^ 1];    // u_{s+sb-1} -> u_{s+sb+1}
            const float ds = src[2 * (sbase + sb)] - src[2 * (sbase + sb) + 1];
            const int cb = 4 * cg;                      // LDS col base (=lx0-3)

            float a[4][4] = {};
            float c[4][4];
            #pragma unroll
            for (int ky = 0; ky < 10; ++ky) {           // 10 rows feed 4 outputs
                const int yy = 4 * band + ky;
                const float4 q0 = *(const float4*)&Fs[yy][cb];
                const float4 q1 = *(const float4*)&Fs[yy][cb + 4];
                const float4 q2 = *(const float4*)&Fs[yy][cb + 8];
                const float v[12] = {q0.x, q0.y, q0.z, q0.w,
                                     q1.x, q1.y, q1.z, q1.w,
                                     q2.x, q2.y, q2.z, q2.w};
                if (ky >= 3 && ky <= 6) {               // center u1 capture
                    c[ky - 3][0] = v[3]; c[ky - 3][1] = v[4];
                    c[ky - 3][2] = v[5]; c[ky - 3][3] = v[6];
                }
                #pragma unroll
                for (int o = 0; o < 4; ++o) {
                    const int kh = ky - o;
                    if (kh >= 0 && kh < 7) {
                        #pragma unroll
                        for (int kx = 0; kx < 7; ++kx) {
                            const float E = eff[kh * 7 + kx];   // uniform s_load
                            a[o][0] = fmaf(v[kx],     E, a[o][0]);
                            a[o][1] = fmaf(v[kx + 1], E, a[o][1]);
                            a[o][2] = fmaf(v[kx + 2], E, a[o][2]);
                            a[o][3] = fmaf(v[kx + 3], E, a[o][3]);
                        }
                    }
                }
            }
            // epilogue: val = D1*conv + u1 + G*(u1-u0)  (+ source at (128,128))
            #pragma unroll
            for (int k = 0; k < 4; ++k) {
                if (k < nR) {
                    const int ly = ly0 + k;
                    const int gy = y0g + ly;
                    #pragma unroll
                    for (int cc = 0; cc < 4; ++cc) {
                        if (cc < nC) {
                            const float u1c = c[k][cc];
                            const float u0c = Fd[ly][lx0 + cc];
                            float val = fmaf(cdv[k][cc], a[k][cc],
                                         fmaf(cgv[k][cc], u1c - u0c, u1c));
                            if (gy == 128 && (x0g + lx0 + cc) == 128)
                                val = fmaf(-cdv[k][cc], ds, val);
                            Fd[ly][lx0 + cc] = val;
                        }
                    }
                }
            }
        }
        __syncthreads();
    }

    // ---- store clean interior: F0 = u_{s+4} -> NU1, F1 = u_{s+3} -> NU0 ----
    {
        const int row = t >> 4, q = (t & 15) * 4;       // 64 rows x 16 float4
        const int gy = by * 64 + row, gx = bx * 64 + q;
        const float4 o1 = *(const float4*)&F[0][12 + row][12 + q];
        const float4 o0 = *(const float4*)&F[1][12 + row][12 + q];
        *(float4*)&NU1[(size_t)b * n1bs + (size_t)(gy + n1off) * n1rs + gx + n1off] = o1;
        *(float4*)&NU0[(size_t)b * PBS + (size_t)(gy + 12) * PC + gx + 12] = o0;
    }
}

extern "C" void kernel_launch(void* const* d_in, const int* in_sizes, int n_in,
                              void* d_out, int out_size, void* d_ws, size_t ws_size,
                              hipStream_t stream) {
    (void)in_sizes; (void)n_in; (void)out_size; (void)ws_size;

    const float* u1    = (const float*)d_in[0];
    const float* u0    = (const float*)d_in[1];
    const float* epsr  = (const float*)d_in[2];
    const float* sigma = (const float*)d_in[3];
    const float* fdk   = (const float*)d_in[4];
    const float* cw    = (const float*)d_in[5];
    const float* src   = (const float*)d_in[6];

    float* eff = (float*)d_ws;          // 64 floats (256 B, keeps A1 16B-aligned)
    float* A1  = eff + 64;
    float* A0  = A1 + NPAD;
    float* B1  = A0 + NPAD;
    float* B0  = B1 + NPAD;
    float* CDg = B0 + NPAD;
    float* CGg = CDg + NPAD;            // total ~30.6 MB of ws

    prep_eff<<<1, 64, 0, stream>>>(fdk, cw, eff);
    prologue<<<(BATCH * PR * (PC / 4) + 255) / 256, 256, 0, stream>>>(
        u1, u0, epsr, sigma, A1, A0, B1, B0, CDg, CGg);

    dim3 grid(4, 4, BATCH);             // 256 blocks = 1/CU
    const float* cu1 = A1;
    const float* cu0 = A0;
    for (int j = 0; j < 8; ++j) {       // 8 x 4 fused steps = 32
        float* n1; float* n0;
        int bs = PBS, rs = PC, off = 12;
        if (j & 1) { n1 = A1; n0 = A0; } else { n1 = B1; n0 = B0; }
        if (j == 7) { n1 = (float*)d_out; bs = NPX; rs = DIM; off = 0; }
        fdtd4<<<grid, 1024, 0, stream>>>(cu1, cu0, CDg, CGg, eff, src,
                                         n1, bs, rs, off, n0, 4 * j);
        cu1 = (j & 1) ? A1 : B1;
        cu0 = (j & 1) ? A0 : B0;
    }
}

// Round 9
// 256.136 us; speedup vs baseline: 2.2224x; 2.2224x over previous
//
#include <hip/hip_runtime.h>

#define DIM   256
#define BATCH 16
#define NPX   (DIM*DIM)

// padded field layout: [280 rows][284 cols], px(gy,gx) at (gy+12, gx+12)
#define PR   280
#define PC   284
#define PBS  (PR*PC)
#define NPAD ((size_t)BATCH*PBS)
// padded coefficient layout, (D1,G) interleaved: float idx = row*568 + 2*(gx+13)+v
#define PCC  568
#define PBSC (PR*PCC)

// LDS: fields [2][90][96] (4-col pad each side), coeffs [84][180] (8-float left pad)
#define LR 90
#define LC 96
#define CR 84
#define CC 180
#define CPAD 8

// Collapse the 14 used fd_kernels into one effective 7x7 kernel.
__global__ void prep_eff(const float* __restrict__ fdk,
                         const float* __restrict__ cw,
                         float* __restrict__ eff) {
    int t = threadIdx.x;
    if (t < 49) {
        float s = 0.f;
        #pragma unroll
        for (int c = 1; c < 15; ++c)
            s += fdk[c * 49 + t] * cw[c - 1];
        eff[t] = s;
    }
}

// XCD-aware streaming prologue: block i -> XCD i&7 -> batches 2(i&7), 2(i&7)+1.
// Builds zero-bordered padded fields and interleaved (D1,G) coefficients.
__global__ __launch_bounds__(1024) void prologue(
    const float* __restrict__ u1, const float* __restrict__ u0,
    const float* __restrict__ epsr, const float* __restrict__ sigma,
    float* __restrict__ A1, float* __restrict__ A0,
    float* __restrict__ B1, float* __restrict__ B0,
    float* __restrict__ CDGg)
{
    const int i = blockIdx.x;
    const int b = 2 * (i & 7) + ((i >> 3) & 1);
    const int slice = i >> 4;                  // 16 slices per batch
    const size_t gb = (size_t)b * NPX;
    const int start = slice * 7455, end = start + 7455;   // 119280/16

    for (int w = start + (int)threadIdx.x; w < end; w += 1024) {
        if (w < 79520) {                       // 4 field arrays, 19880 f4 each
            const int kind = w / 19880;        // 0:A1 1:A0 2:B1 3:B0
            const int cell = w - kind * 19880;
            const int row = cell / 71, c4 = (cell - row * 71) * 4;
            float4 v = make_float4(0.f, 0.f, 0.f, 0.f);
            if (kind < 2) {
                const float* sp = kind ? u0 : u1;
                const int gy = row - 12;
                if (gy >= 0 && gy < DIM) {
                    #pragma unroll
                    for (int k = 0; k < 4; ++k) {
                        const int gx = c4 + k - 12;
                        if (gx >= 0 && gx < DIM)
                            ((float*)&v)[k] = sp[gb + gy * DIM + gx];
                    }
                }
            }
            float* dst = (kind == 0) ? A1 : (kind == 1) ? A0 : (kind == 2) ? B1 : B0;
            *(float4*)&dst[(size_t)b * PBS + (size_t)row * PC + c4] = v;
        } else {                               // CDG: 39760 f4 (2 px per f4)
            const int cell = w - 79520;
            const int row = cell / 142, c4 = cell - row * 142;
            const int gy = row - 12;
            float4 v = make_float4(0.f, 0.f, 0.f, 0.f);
            #pragma unroll
            for (int p = 0; p < 2; ++p) {
                const int gx = 2 * c4 - 13 + p;
                if (gy >= 0 && gy < DIM && gx >= 0 && gx < DIM) {
                    const float e = epsr[gb + gy * DIM + gx];
                    const float s = sigma[gb + gy * DIM + gx];
                    const float d = 1.f / (4.f * e + s);   // exact div once
                    ((float*)&v)[2 * p]     = d;
                    ((float*)&v)[2 * p + 1] = (4.f * e - s) * d;
                }
            }
            *(float4*)&CDGg[(size_t)b * PBSC + (size_t)row * PCC + 4 * c4] = v;
        }
    }
}

// One fused sub-step. Outputs on an absolute 4-col grid (phys cols 4j..4j+3,
// j in [J0, J0+NG)): all LDS reads are aligned b128, lanes contiguous ->
// conflict-free. Edge pixels outside the logical region are computed into Fd
// but provably never consumed (next substep's valid taps stay inside region).
template<int NB, int NG, int J0, int OFF>
__device__ __forceinline__ void substep(
    const float (*__restrict__ Fs)[LC], float (*__restrict__ Fd)[LC],
    const float (*__restrict__ CDG)[CC], const float* __restrict__ eff,
    float ds, bool srcHere, int t)
{
    constexpr int SLOTS = NB * NG;
    if (t < SLOTS) {
        const int band = t / NG;               // compile-time divisor
        const int j    = J0 + (t - band * NG);
        const int pcol = 4 * j;                // physical col of 4 owned px
        const int yb   = OFF + 4 * band;       // first of 4 owned rows

        float a[4][4] = {{0,0,0,0},{0,0,0,0},{0,0,0,0},{0,0,0,0}};
        #pragma unroll
        for (int ky = 0; ky < 10; ++ky) {      // 10 rows feed 4 output rows
            const int row = yb - 3 + ky;
            const float4 q0 = *(const float4*)&Fs[row][pcol - 4];
            const float4 q1 = *(const float4*)&Fs[row][pcol];
            const float4 q2 = *(const float4*)&Fs[row][pcol + 4];
            const float v[12] = {q0.x,q0.y,q0.z,q0.w, q1.x,q1.y,q1.z,q1.w,
                                 q2.x,q2.y,q2.z,q2.w};
            #pragma unroll
            for (int o = 0; o < 4; ++o) {
                const int kh = ky - o;
                if (kh >= 0 && kh < 7) {
                    #pragma unroll
                    for (int kx = 0; kx < 7; ++kx) {
                        const float E = eff[kh * 7 + kx];   // uniform s_load
                        a[o][0] = fmaf(v[kx + 1], E, a[o][0]);
                        a[o][1] = fmaf(v[kx + 2], E, a[o][1]);
                        a[o][2] = fmaf(v[kx + 3], E, a[o][2]);
                        a[o][3] = fmaf(v[kx + 4], E, a[o][3]);
                    }
                }
            }
        }
        // epilogue: val = D1*conv + u1 + G*(u1-u0); all b128/b64, contiguous
        #pragma unroll
        for (int o = 0; o < 4; ++o) {
            const int row = yb + o;
            const float4 u1q = *(const float4*)&Fs[row][pcol];
            const float4 u0q = *(const float4*)&Fd[row][pcol];
            const float* cg = &CDG[row - 3][2 * pcol - 14 + CPAD];
            const float2 dg0 = *(const float2*)&cg[0];
            const float2 dg1 = *(const float2*)&cg[2];
            const float2 dg2 = *(const float2*)&cg[4];
            const float2 dg3 = *(const float2*)&cg[6];
            float4 r;
            r.x = fmaf(dg0.x, a[o][0], fmaf(dg0.y, u1q.x - u0q.x, u1q.x));
            r.y = fmaf(dg1.x, a[o][1], fmaf(dg1.y, u1q.y - u0q.y, u1q.y));
            r.z = fmaf(dg2.x, a[o][2], fmaf(dg2.y, u1q.z - u0q.z, u1q.z));
            r.w = fmaf(dg3.x, a[o][3], fmaf(dg3.y, u1q.w - u0q.w, u1q.w));
            if (srcHere && row == 12 && pcol == 16)        // px (128,128)
                r.x = fmaf(-dg0.x, ds, r.x);
            *(float4*)&Fd[row][pcol] = r;
        }
    }
}

// 4 FDTD steps per launch. 256 blocks = 1/CU; block i -> XCD i&7, batch
// 2(i&7)+((i>>3)&1), tile i>>4 -> the same XCD re-reads the same 2 batches
// every dispatch (slab ~2.5-3.8 MB fits the 4 MB per-XCD L2).
__global__ __launch_bounds__(1024) void fdtd4(
    const float* __restrict__ U1, const float* __restrict__ U0,   // padded
    const float* __restrict__ CDGg, const float* __restrict__ eff,
    const float* __restrict__ src,
    float* __restrict__ NU1, int n1bs, int n1rs, int n1off,
    float* __restrict__ NU0, int sbase)
{
    __shared__ __align__(16) float F[2][LR][LC];   // 69.1 KB
    __shared__ __align__(16) float CDG[CR][CC];    // 60.5 KB

    const int t = threadIdx.x;
    const int i = blockIdx.x;
    const int b    = 2 * (i & 7) + ((i >> 3) & 1);
    const int tile = i >> 4;
    const int bx = tile & 3, by = tile >> 2;
    const bool srcHere = (bx == 2 && by == 2);
    const size_t pbF = (size_t)b * PBS;
    const size_t pbC = (size_t)b * PBSC;

    // ---- stage fields (88 rows x 22 f4 each) and coeffs (82 x 41 f4) ----
    {
        const float* s1 = U1 + pbF;
        const float* s0 = U0 + pbF;
        #pragma unroll
        for (int rep = 0; rep < 4; ++rep) {
            const int idx = t + rep * 1024;
            if (idx < 2 * 1936) {
                const int arr = idx >= 1936 ? 1 : 0;
                const int j2  = idx - arr * 1936;
                const int row = j2 / 22, c4 = (j2 - row * 22) * 4;
                const float4 v = *(const float4*)
                    &(arr ? s0 : s1)[(size_t)(by * 64 + row) * PC + bx * 64 + c4];
                *(float4*)&F[arr][row][4 + c4] = v;
            }
        }
        #pragma unroll
        for (int rep = 0; rep < 4; ++rep) {
            const int idx = t + rep * 1024;
            if (idx < 82 * 41) {
                const int row = idx / 41, c4 = (idx - row * 41) * 4;
                const float4 v = *(const float4*)
                    &CDGg[pbC + (size_t)(by * 64 + 3 + row) * PCC + 128 * bx + 8 + c4];
                *(float4*)&CDG[row][CPAD + c4] = v;
            }
        }
    }
    __syncthreads();

    const float ds0 = src[2 * sbase]     - src[2 * sbase + 1];
    const float ds1 = src[2 * sbase + 2] - src[2 * sbase + 3];
    const float ds2 = src[2 * sbase + 4] - src[2 * sbase + 5];
    const float ds3 = src[2 * sbase + 6] - src[2 * sbase + 7];

    substep<21, 22, 1,  3>(F[0], F[1], CDG, eff, ds0, srcHere, t); __syncthreads();
    substep<19, 20, 2,  6>(F[1], F[0], CDG, eff, ds1, srcHere, t); __syncthreads();
    substep<18, 18, 3,  9>(F[0], F[1], CDG, eff, ds2, srcHere, t); __syncthreads();
    substep<16, 16, 4, 12>(F[1], F[0], CDG, eff, ds3, srcHere, t); __syncthreads();

    // ---- store clean 64x64 interior: F0 = u_{s+4}, F1 = u_{s+3} ----
    {
        const int row = t >> 4, c = (t & 15) * 4;
        const int gy = by * 64 + row, gx = bx * 64 + c;
        const float4 o1 = *(const float4*)&F[0][12 + row][16 + c];
        const float4 o0 = *(const float4*)&F[1][12 + row][16 + c];
        *(float4*)&NU1[(size_t)b * n1bs + (size_t)(gy + n1off) * n1rs + gx + n1off] = o1;
        *(float4*)&NU0[pbF + (size_t)(gy + 12) * PC + gx + 12] = o0;
    }
}

extern "C" void kernel_launch(void* const* d_in, const int* in_sizes, int n_in,
                              void* d_out, int out_size, void* d_ws, size_t ws_size,
                              hipStream_t stream) {
    (void)in_sizes; (void)n_in; (void)out_size; (void)ws_size;

    const float* u1    = (const float*)d_in[0];
    const float* u0    = (const float*)d_in[1];
    const float* epsr  = (const float*)d_in[2];
    const float* sigma = (const float*)d_in[3];
    const float* fdk   = (const float*)d_in[4];
    const float* cw    = (const float*)d_in[5];
    const float* src   = (const float*)d_in[6];

    float* eff  = (float*)d_ws;         // 64 floats, keeps arrays 16B-aligned
    float* A1   = eff + 64;
    float* A0   = A1 + NPAD;
    float* B1   = A0 + NPAD;
    float* B0   = B1 + NPAD;
    float* CDGg = B0 + NPAD;            // BATCH*PBSC floats; ws total ~30.5 MB

    prep_eff<<<1, 64, 0, stream>>>(fdk, cw, eff);
    prologue<<<256, 1024, 0, stream>>>(u1, u0, epsr, sigma, A1, A0, B1, B0, CDGg);

    for (int j = 0; j < 8; ++j) {       // 8 x 4 fused steps = 32
        const float* cu1 = (j & 1) ? B1 : A1;
        const float* cu0 = (j & 1) ? B0 : A0;
        float* n1 = (j & 1) ? A1 : B1;
        float* n0 = (j & 1) ? A0 : B0;
        int bs = PBS, rs = PC, off = 12;
        if (j == 7) { n1 = (float*)d_out; bs = NPX; rs = DIM; off = 0; }
        fdtd4<<<256, 1024, 0, stream>>>(cu1, cu0, CDGg, eff, src,
                                        n1, bs, rs, off, n0, 4 * j);
    }
}

// Round 10
// 248.093 us; speedup vs baseline: 2.2945x; 1.0324x over previous
//
#include <hip/hip_runtime.h>

#define DIM   256
#define BATCH 16
#define NPX   (DIM*DIM)

// all padded global arrays share one layout: [280 rows][284 cols],
// px(gy,gx) at (gy+12, gx+12); zeros outside the image.
#define PR   280
#define PC   284
#define PBS  (PR*PC)
#define NPAD ((size_t)BATCH*PBS)

// LDS: fields [2][90][100], coeff planes [84][100].
// LC=100 -> row stride 400B = 16 banks mod 32: a wave's 4-row bands hit
// banks +0/+16/+0 -> worst 2-way alias (free, m136). LC%4==0 keeps b128 align.
#define LR 90
#define LC 100
#define CR 84

// Collapse the 14 used fd_kernels into one effective 7x7 kernel.
__global__ void prep_eff(const float* __restrict__ fdk,
                         const float* __restrict__ cw,
                         float* __restrict__ eff) {
    int t = threadIdx.x;
    if (t < 49) {
        float s = 0.f;
        #pragma unroll
        for (int c = 1; c < 15; ++c)
            s += fdk[c * 49 + t] * cw[c - 1];
        eff[t] = s;
    }
}

// XCD-aware streaming prologue: block i -> XCD i&7 -> batch 2(i&7)+((i>>3)&1).
// Builds 6 identically-padded planes: A1,A0 (fields), B1,B0 (zeroed ping-pong),
// CDp = 1/(4e+sg), CGp = (4e-sg)/(4e+sg).
__global__ __launch_bounds__(1024) void prologue(
    const float* __restrict__ u1, const float* __restrict__ u0,
    const float* __restrict__ epsr, const float* __restrict__ sigma,
    float* __restrict__ A1, float* __restrict__ A0,
    float* __restrict__ B1, float* __restrict__ B0,
    float* __restrict__ CDp, float* __restrict__ CGp)
{
    const int i = blockIdx.x;
    const int b = 2 * (i & 7) + ((i >> 3) & 1);
    const int slice = i >> 4;                  // 16 slices per batch
    const size_t gb = (size_t)b * NPX;
    const int start = slice * 7455, end = start + 7455;   // 6*19880/16

    for (int w = start + (int)threadIdx.x; w < end; w += 1024) {
        const int kind = w / 19880;            // 0:A1 1:A0 2:B1 3:B0 4:CD 5:CG
        const int cell = w - kind * 19880;
        const int row = cell / 71, c4 = (cell - row * 71) * 4;
        const int gy = row - 12;
        float4 v = make_float4(0.f, 0.f, 0.f, 0.f);
        if (kind < 2) {
            const float* sp = kind ? u0 : u1;
            if (gy >= 0 && gy < DIM) {
                #pragma unroll
                for (int k = 0; k < 4; ++k) {
                    const int gx = c4 + k - 12;
                    if (gx >= 0 && gx < DIM)
                        ((float*)&v)[k] = sp[gb + gy * DIM + gx];
                }
            }
        } else if (kind >= 4) {
            if (gy >= 0 && gy < DIM) {
                #pragma unroll
                for (int k = 0; k < 4; ++k) {
                    const int gx = c4 + k - 12;
                    if (gx >= 0 && gx < DIM) {
                        const float e = epsr[gb + gy * DIM + gx];
                        const float s = sigma[gb + gy * DIM + gx];
                        const float d = 1.f / (4.f * e + s);   // exact div once
                        ((float*)&v)[k] = (kind == 4) ? d : (4.f * e - s) * d;
                    }
                }
            }
        }
        float* dst = (kind == 0) ? A1 : (kind == 1) ? A0 : (kind == 2) ? B1
                   : (kind == 3) ? B0 : (kind == 4) ? CDp : CGp;
        *(float4*)&dst[(size_t)b * PBS + (size_t)row * PC + c4] = v;
    }
}

// One fused sub-step. Outputs on an absolute 4-col grid (phys cols 4j..4j+3,
// j in [J0, J0+NG)): all LDS accesses are aligned b128 with contiguous lanes.
// Edge pixels outside the logical region are computed but provably never
// consumed (next substep's valid taps stay inside its region).
template<int NB, int NG, int J0, int OFF>
__device__ __forceinline__ void substep(
    const float (*__restrict__ Fs)[LC], float (*__restrict__ Fd)[LC],
    const float (*__restrict__ CD)[LC], const float (*__restrict__ CG)[LC],
    const float* __restrict__ eff, float ds, bool srcHere, int t)
{
    constexpr int SLOTS = NB * NG;
    if (t < SLOTS) {
        const int band = t / NG;               // compile-time divisor
        const int j    = J0 + (t - band * NG);
        const int pcol = 4 * j;                // physical col of 4 owned px
        const int yb   = OFF + 4 * band;       // first of 4 owned rows

        float a[4][4] = {{0,0,0,0},{0,0,0,0},{0,0,0,0},{0,0,0,0}};
        #pragma unroll
        for (int ky = 0; ky < 10; ++ky) {      // 10 rows feed 4 output rows
            const int row = yb - 3 + ky;
            const float4 q0 = *(const float4*)&Fs[row][pcol - 4];
            const float4 q1 = *(const float4*)&Fs[row][pcol];
            const float4 q2 = *(const float4*)&Fs[row][pcol + 4];
            const float v[12] = {q0.x,q0.y,q0.z,q0.w, q1.x,q1.y,q1.z,q1.w,
                                 q2.x,q2.y,q2.z,q2.w};
            #pragma unroll
            for (int o = 0; o < 4; ++o) {
                const int kh = ky - o;
                if (kh >= 0 && kh < 7) {
                    #pragma unroll
                    for (int kx = 0; kx < 7; ++kx) {
                        const float E = eff[kh * 7 + kx];   // uniform s_load
                        a[o][0] = fmaf(v[kx + 1], E, a[o][0]);
                        a[o][1] = fmaf(v[kx + 2], E, a[o][1]);
                        a[o][2] = fmaf(v[kx + 3], E, a[o][2]);
                        a[o][3] = fmaf(v[kx + 4], E, a[o][3]);
                    }
                }
            }
        }
        // epilogue: val = D1*conv + u1 + G*(u1-u0); all aligned b128 reads
        #pragma unroll
        for (int o = 0; o < 4; ++o) {
            const int row = yb + o;
            const float4 u1q = *(const float4*)&Fs[row][pcol];
            const float4 u0q = *(const float4*)&Fd[row][pcol];
            const float4 dq  = *(const float4*)&CD[row - 3][pcol];
            const float4 gq  = *(const float4*)&CG[row - 3][pcol];
            float4 r;
            r.x = fmaf(dq.x, a[o][0], fmaf(gq.x, u1q.x - u0q.x, u1q.x));
            r.y = fmaf(dq.y, a[o][1], fmaf(gq.y, u1q.y - u0q.y, u1q.y));
            r.z = fmaf(dq.z, a[o][2], fmaf(gq.z, u1q.z - u0q.z, u1q.z));
            r.w = fmaf(dq.w, a[o][3], fmaf(gq.w, u1q.w - u0q.w, u1q.w));
            if (srcHere && row == 12 && pcol == 16)        // px (128,128)
                r.x = fmaf(-dq.x, ds, r.x);
            *(float4*)&Fd[row][pcol] = r;
        }
    }
}

// 4 FDTD steps per launch. 256 blocks = 1/CU; block i -> XCD i&7, batch
// 2(i&7)+((i>>3)&1), tile i>>4 -> each XCD re-reads the same ~3 MB slab
// every dispatch (fits its private 4 MB L2).
__global__ __launch_bounds__(1024) void fdtd4(
    const float* __restrict__ U1, const float* __restrict__ U0,   // padded
    const float* __restrict__ CDg, const float* __restrict__ CGg, // padded
    const float* __restrict__ eff, const float* __restrict__ src,
    float* __restrict__ NU1, int n1bs, int n1rs, int n1off,
    float* __restrict__ NU0, int sbase)
{
    __shared__ __align__(16) float F[2][LR][LC];     // 72.0 KB
    __shared__ __align__(16) float CD[CR][LC];       // 33.6 KB
    __shared__ __align__(16) float CG[CR][LC];       // 33.6 KB

    const int t = threadIdx.x;
    const int i = blockIdx.x;
    const int b    = 2 * (i & 7) + ((i >> 3) & 1);
    const int tile = i >> 4;
    const int bx = tile & 3, by = tile >> 2;
    const bool srcHere = (bx == 2 && by == 2);
    const size_t pbF = (size_t)b * PBS;

    // ---- stage fields (88 rows x 22 f4 each) + coeffs (84 rows x 22 f4 each),
    //      LDS col 4+c <- padded-global col bx*64+c ----
    {
        const float* s1 = U1 + pbF;
        const float* s0 = U0 + pbF;
        const float* sd = CDg + pbF;
        const float* sg = CGg + pbF;
        #pragma unroll
        for (int rep = 0; rep < 4; ++rep) {
            const int idx = t + rep * 1024;
            if (idx < 2 * 1936) {
                const int arr = idx >= 1936 ? 1 : 0;
                const int j2  = idx - arr * 1936;
                const int row = j2 / 22, c4 = (j2 - row * 22) * 4;
                const float4 v = *(const float4*)
                    &(arr ? s0 : s1)[(size_t)(by * 64 + row) * PC + bx * 64 + c4];
                *(float4*)&F[arr][row][4 + c4] = v;
            }
        }
        #pragma unroll
        for (int rep = 0; rep < 4; ++rep) {
            const int idx = t + rep * 1024;
            if (idx < 2 * 1848) {                      // 84 rows x 22 f4
                const int arr = idx >= 1848 ? 1 : 0;
                const int j2  = idx - arr * 1848;
                const int row = j2 / 22, c4 = (j2 - row * 22) * 4;
                const float4 v = *(const float4*)
                    &(arr ? sg : sd)[(size_t)(by * 64 + 3 + row) * PC + bx * 64 + c4];
                if (arr) *(float4*)&CG[row][4 + c4] = v;
                else     *(float4*)&CD[row][4 + c4] = v;
            }
        }
    }
    __syncthreads();

    const float ds0 = src[2 * sbase]     - src[2 * sbase + 1];
    const float ds1 = src[2 * sbase + 2] - src[2 * sbase + 3];
    const float ds2 = src[2 * sbase + 4] - src[2 * sbase + 5];
    const float ds3 = src[2 * sbase + 6] - src[2 * sbase + 7];

    substep<21, 22, 1,  3>(F[0], F[1], CD, CG, eff, ds0, srcHere, t); __syncthreads();
    substep<19, 20, 2,  6>(F[1], F[0], CD, CG, eff, ds1, srcHere, t); __syncthreads();
    substep<18, 18, 3,  9>(F[0], F[1], CD, CG, eff, ds2, srcHere, t); __syncthreads();
    substep<16, 16, 4, 12>(F[1], F[0], CD, CG, eff, ds3, srcHere, t); __syncthreads();

    // ---- store clean 64x64 interior: F0 = u_{s+4}, F1 = u_{s+3} ----
    {
        const int row = t >> 4, c = (t & 15) * 4;
        const int gy = by * 64 + row, gx = bx * 64 + c;
        const float4 o1 = *(const float4*)&F[0][12 + row][16 + c];
        const float4 o0 = *(const float4*)&F[1][12 + row][16 + c];
        *(float4*)&NU1[(size_t)b * n1bs + (size_t)(gy + n1off) * n1rs + gx + n1off] = o1;
        *(float4*)&NU0[pbF + (size_t)(gy + 12) * PC + gx + 12] = o0;
    }
}

extern "C" void kernel_launch(void* const* d_in, const int* in_sizes, int n_in,
                              void* d_out, int out_size, void* d_ws, size_t ws_size,
                              hipStream_t stream) {
    (void)in_sizes; (void)n_in; (void)out_size; (void)ws_size;

    const float* u1    = (const float*)d_in[0];
    const float* u0    = (const float*)d_in[1];
    const float* epsr  = (const float*)d_in[2];
    const float* sigma = (const float*)d_in[3];
    const float* fdk   = (const float*)d_in[4];
    const float* cw    = (const float*)d_in[5];
    const float* src   = (const float*)d_in[6];

    float* eff = (float*)d_ws;          // 64 floats, keeps arrays 16B-aligned
    float* A1  = eff + 64;
    float* A0  = A1 + NPAD;
    float* B1  = A0 + NPAD;
    float* B0  = B1 + NPAD;
    float* CDg = B0 + NPAD;
    float* CGg = CDg + NPAD;            // 6 planes x 5.1 MB ~= 30.5 MB ws

    prep_eff<<<1, 64, 0, stream>>>(fdk, cw, eff);
    prologue<<<256, 1024, 0, stream>>>(u1, u0, epsr, sigma, A1, A0, B1, B0, CDg, CGg);

    for (int j = 0; j < 8; ++j) {       // 8 x 4 fused steps = 32
        const float* cu1 = (j & 1) ? B1 : A1;
        const float* cu0 = (j & 1) ? B0 : A0;
        float* n1 = (j & 1) ? A1 : B1;
        float* n0 = (j & 1) ? A0 : B0;
        int bs = PBS, rs = PC, off = 12;
        if (j == 7) { n1 = (float*)d_out; bs = NPX; rs = DIM; off = 0; }
        fdtd4<<<256, 1024, 0, stream>>>(cu1, cu0, CDg, CGg, eff, src,
                                        n1, bs, rs, off, n0, 4 * j);
    }
}